// Round 2
// baseline (5002.382 us; speedup 1.0000x reference)
//
#include <hip/hip_runtime.h>
#include <hip/hip_bf16.h>

#define EDIM 256
#define HDIM 512
#define BB 32
#define SS 512
#define CC 2
#define G3 1536   // 3*HDIM

typedef unsigned int u32;
typedef unsigned long long u64;
typedef __attribute__((ext_vector_type(8))) short short8;
typedef __attribute__((ext_vector_type(4))) float f32x4;

__device__ __forceinline__ float toF(float v) { return v; }
__device__ __forceinline__ float toF(__hip_bfloat16 v) { return __bfloat162float(v); }
__device__ __forceinline__ void storeX(float* p, float v) { *p = v; }
__device__ __forceinline__ void storeX(__hip_bfloat16* p, float v) { *p = __float2bfloat16(v); }

// fp32 -> bf16 bits, round-to-nearest-even (no dependence on __hip_bfloat16 internals)
__device__ __forceinline__ unsigned short f2bf(float f) {
  u32 b = __float_as_uint(f);
  return (unsigned short)((b + 0x7FFFu + ((b >> 16) & 1u)) >> 16);
}

// ---------------- K1: zero tagged h words (wgs 0..15) + flags (wg 17) + induced vec (wg 16) --------
__global__ void k_init(const float* __restrict__ induction, const float* __restrict__ unk_vec,
                       float* __restrict__ induced, u64* __restrict__ thw) {
  const int t = threadIdx.x;
  const int wg = blockIdx.x;
  if (wg < 16) {
    u64* p = thw + (size_t)wg * 1024;  // 16*1024 = 8 groups * 2 * 1024 data words
    for (int i = t; i < 1024; i += 256) p[i] = 0ull;
  } else if (wg == 17) {
    u64* f = thw + 16384;              // flag region: 8 groups * 256 u32 = 8KB = 1024 u64
    for (int i = t; i < 1024; i += 256) f[i] = 0ull;
  } else {
    float acc = 0.f;
    const float* row = induction + t * EDIM;
#pragma unroll 4
    for (int j = 0; j < EDIM; j += 4) {
      float4 a = *(const float4*)(row + j);
      float4 u = *(const float4*)(unk_vec + j);
      acc += a.x * u.x + a.y * u.y + a.z * u.z + a.w * u.w;
    }
    induced[t] = acc;
  }
}

// ---------------- K2: xi = gather(e) @ W_ih^T + b_ih via bf16 MFMA ----------------------------------
// 128x128 tile, K-chunks of 32. A/B staged fp32->bf16 in LDS. mfma_f32_16x16x32_bf16.
template <typename XT>
__global__ __launch_bounds__(256) void k_xi(const int* __restrict__ x, const float* __restrict__ emb,
                                            const float* __restrict__ induced,
                                            const float* __restrict__ W_ih, const float* __restrict__ b_ih,
                                            XT* __restrict__ xi) {
  __shared__ __align__(16) unsigned short As[128][40];  // 32 k + 8 pad (80B rows, 16B-aligned)
  __shared__ __align__(16) unsigned short Bs[128][40];
  __shared__ int toks[128];
  __shared__ float bcol[128];
  const int c0 = blockIdx.x * 128;
  const int r0 = blockIdx.y * 128;
  const int tid = threadIdx.x;
  if (tid < 128) { toks[tid] = x[r0 + tid]; bcol[tid] = b_ih[c0 + tid]; }
  __syncthreads();

  const int wv = tid >> 6, ln = tid & 63;
  const int lr = tid & 127, kh = tid >> 7;   // staging: row, k-half (16 k's each)
  const int fm = ln & 15, fq = ln >> 4;      // fragment lane decomposition

  f32x4 acc[2][8];
#pragma unroll
  for (int i = 0; i < 2; i++)
#pragma unroll
    for (int j = 0; j < 8; j++) acc[i][j] = (f32x4){0.f, 0.f, 0.f, 0.f};

  const int tok = toks[lr];
  const float* abase = (tok < 0 ? induced : emb + (size_t)tok * EDIM) + kh * 16;
  const float* bbase = W_ih + (size_t)(c0 + lr) * EDIM + kh * 16;

  for (int kk = 0; kk < EDIM; kk += 32) {
    unsigned short av[16], bv[16];
#pragma unroll
    for (int q = 0; q < 4; q++) {
      float4 ta = *(const float4*)(abase + kk + q * 4);
      float4 tb = *(const float4*)(bbase + kk + q * 4);
      av[q * 4 + 0] = f2bf(ta.x); av[q * 4 + 1] = f2bf(ta.y);
      av[q * 4 + 2] = f2bf(ta.z); av[q * 4 + 3] = f2bf(ta.w);
      bv[q * 4 + 0] = f2bf(tb.x); bv[q * 4 + 1] = f2bf(tb.y);
      bv[q * 4 + 2] = f2bf(tb.z); bv[q * 4 + 3] = f2bf(tb.w);
    }
    *(uint4*)&As[lr][kh * 16 + 0] = *(uint4*)&av[0];
    *(uint4*)&As[lr][kh * 16 + 8] = *(uint4*)&av[8];
    *(uint4*)&Bs[lr][kh * 16 + 0] = *(uint4*)&bv[0];
    *(uint4*)&Bs[lr][kh * 16 + 8] = *(uint4*)&bv[8];
    __syncthreads();

    short8 af0 = *(const short8*)&As[wv * 32 + fm][fq * 8];
    short8 af1 = *(const short8*)&As[wv * 32 + 16 + fm][fq * 8];
#pragma unroll
    for (int ni = 0; ni < 8; ni++) {
      short8 bf = *(const short8*)&Bs[ni * 16 + fm][fq * 8];
      acc[0][ni] = __builtin_amdgcn_mfma_f32_16x16x32_bf16(af0, bf, acc[0][ni], 0, 0, 0);
      acc[1][ni] = __builtin_amdgcn_mfma_f32_16x16x32_bf16(af1, bf, acc[1][ni], 0, 0, 0);
    }
    __syncthreads();
  }

#pragma unroll
  for (int mi = 0; mi < 2; mi++)
#pragma unroll
    for (int ni = 0; ni < 8; ni++) {
      const int col = c0 + ni * 16 + fm;
      const float bb = bcol[ni * 16 + fm];
#pragma unroll
      for (int r = 0; r < 4; r++) {
        const int row = r0 + wv * 32 + mi * 16 + fq * 4 + r;
        storeX(xi + (size_t)row * G3 + col, acc[mi][ni][r] + bb);
      }
    }
}

// ---------------- K3: persistent GRU, flag-released tagged exchange --------------------------------
// 8 groups x 32 wgs. Data word W = c*256+p (unchanged): 24-bit mantissa fp32 pair + 16-bit step tag,
// relaxed agent-scope u64, double-buffered by step parity.
//
// NEW exchange protocol (R2): per-producer-WAVE flags. Producer wave: 8 packet stores ->
// s_waitcnt vmcnt(0) (agent-release) -> 1 u32 flag store (value s+1, monotone). Consumers poll ONLY
// the 128 flags of their group (512B, 8 cache lines; 2 flags/lane + __any ballot) instead of
// re-loading 8KB of data words -> ~16x less L2 spin traffic, data words loaded once. Tag verify on
// data words kept as a zero-iteration safety net. xi prefetch moved AFTER the release so vmcnt(0)
// never drains an HBM-latency load.
template <typename XT>
__global__ __launch_bounds__(256, 1) void k_gru(const XT* __restrict__ xi, const float* __restrict__ W_hh,
                                                const float* __restrict__ b_hh, u64* __restrict__ thw,
                                                float* __restrict__ pooled) {
  const int wg = blockIdx.x;
  const int g = wg & 7;          // group (mod-8 keeps a group's wgs on one XCD)
  const int m = wg >> 3;         // 0..31
  const int bbase = g * 4;
  const int i0 = m * 16;
  const int tid = threadIdx.x;
  const int iu = tid >> 4;       // 0..15: unit within wg slice
  const int ks = tid & 15;       // 0..15: k-slice, k in [ks*32, ks*32+32)
  const int i = i0 + iu;         // global unit
  const int swz = ks & 7;        // LDS chunk swizzle for this lane's window

  // per-thread W_hh slice: 3 gates x 32 k as 8 float4 (96 VGPRs; occupancy is 1 wave/SIMD anyway)
  f32x4 w[3][8];
#pragma unroll
  for (int q = 0; q < 3; q++) {
    const float* wr = W_hh + (size_t)(q * HDIM + i) * HDIM + ks * 32;
#pragma unroll
    for (int j = 0; j < 8; j++) w[q][j] = *(const f32x4*)(wr + j * 4);
  }
  const float bh0 = b_hh[i], bh1 = b_hh[HDIM + i], bh2 = b_hh[2 * HDIM + i];

  const bool gate = (ks < 4);
  const int gb = ks & 3;         // batch-in-group for gate lanes
  // h_prev read index for unit i in a swizzled row: chunk Q=i>>2, phys=Q^((Q>>3)&7), elem=i&3
  const int hpIdx = ((((i >> 2) ^ ((i >> 5) & 7)) << 2) | (i & 3));
  // staging write offset for pair p=tid: chunk Q=tid>>1, phys=Q^((Q>>3)&7), elem=(tid&1)*2
  const int foff = ((((tid >> 1) ^ ((tid >> 4) & 7)) << 2) | ((tid & 1) << 1));

  u64* slot = thw + (size_t)g * 2 * 1024;
  u32* fl = (u32*)(thw + 16384) + g * 256;  // 128 wave-flags used, padded to 1KB/group
  const int myflag = m * 4 + (tid >> 6);
  const int ln = tid & 63;

  __shared__ __align__(16) float hs[2][4][512];

  float pmax = -3.0e38f;

  float cxr = 0.f, cxz = 0.f, cxn = 0.f;
  if (gate) {
    const size_t xo = (size_t)(bbase + gb) * SS * G3 + i;
    cxr = toF(xi[xo]); cxz = toF(xi[xo + HDIM]); cxn = toF(xi[xo + 2 * HDIM]);
  }

  for (int s = 0; s < SS; s++) {
    float* hb = &hs[s & 1][0][0];
    if (s == 0) {
#pragma unroll
      for (int t = 0; t < 8; t++) hb[t * 256 + tid] = 0.f;
    } else {
      const u32 need = (u32)s;
      // ---- wave-parallel flag poll: 2 of 128 flags per lane, monotone >= compare ----
      {
        u32 fa = __hip_atomic_load(fl + ln, __ATOMIC_RELAXED, __HIP_MEMORY_SCOPE_AGENT);
        u32 fb = __hip_atomic_load(fl + 64 + ln, __ATOMIC_RELAXED, __HIP_MEMORY_SCOPE_AGENT);
        int guard = 0;
        while (__any((fa < need) || (fb < need)) && guard < (1 << 20)) {
          __builtin_amdgcn_s_sleep(1);
          if (fa < need) fa = __hip_atomic_load(fl + ln, __ATOMIC_RELAXED, __HIP_MEMORY_SCOPE_AGENT);
          if (fb < need) fb = __hip_atomic_load(fl + 64 + ln, __ATOMIC_RELAXED, __HIP_MEMORY_SCOPE_AGENT);
          guard++;
        }
      }
      asm volatile("" ::: "memory");  // pin data loads after the poll (compiler ordering)
      // ---- single burst of data loads; tag verify is a zero-iteration safety net ----
      const u64* src = slot + (size_t)(s & 1) * 1024 + tid;  // W = j*256+tid -> chain j, pair tid
      u64 v[4];
#pragma unroll
      for (int j = 0; j < 4; j++)
        v[j] = __hip_atomic_load(src + j * 256, __ATOMIC_RELAXED, __HIP_MEMORY_SCOPE_AGENT);
      u32 pend = 0;
#pragma unroll
      for (int j = 0; j < 4; j++)
        if ((u32)(v[j] & 0xFFFFu) != need) pend |= 1u << j;
      int guard = 0;
      while (pend && guard < (1 << 20)) {
        __builtin_amdgcn_s_sleep(1);
#pragma unroll
        for (int j = 0; j < 4; j++)
          if (pend & (1u << j))
            v[j] = __hip_atomic_load(src + j * 256, __ATOMIC_RELAXED, __HIP_MEMORY_SCOPE_AGENT);
#pragma unroll
        for (int j = 0; j < 4; j++)
          if ((pend & (1u << j)) && (u32)(v[j] & 0xFFFFu) == need) pend &= ~(1u << j);
        guard++;
      }
#pragma unroll
      for (int j = 0; j < 4; j++) {
        const float a = __uint_as_float((u32)(v[j] >> 40) << 8);
        const float b = __uint_as_float((u32)((v[j] >> 16) & 0xFFFFFFu) << 8);
        *(float2*)&hb[j * 512 + foff] = make_float2(a, b);
      }
    }
    __syncthreads();  // the ONLY barrier per step

    // dots: 4 batches x 3 gates over this lane's 32-k window (float4 lanes, swizzled chunks)
    f32x4 acc[4][3];
#pragma unroll
    for (int b = 0; b < 4; b++)
#pragma unroll
      for (int q = 0; q < 3; q++) acc[b][q] = (f32x4){0.f, 0.f, 0.f, 0.f};

#pragma unroll
    for (int b = 0; b < 4; b++) {
      const float* hr = hb + b * 512 + ks * 32;
#pragma unroll
      for (int j = 0; j < 8; j++) {
        const f32x4 hv = *(const f32x4*)(hr + ((j ^ swz) << 2));  // logical chunk j
        acc[b][0] = __builtin_elementwise_fma(w[0][j], hv, acc[b][0]);
        acc[b][1] = __builtin_elementwise_fma(w[1][j], hv, acc[b][1]);
        acc[b][2] = __builtin_elementwise_fma(w[2][j], hv, acc[b][2]);
      }
    }

    // horizontal collapse to 12 scalars
    float ha[4][3];
#pragma unroll
    for (int b = 0; b < 4; b++)
#pragma unroll
      for (int q = 0; q < 3; q++) {
        const f32x4 t = acc[b][q];
        ha[b][q] = (t.x + t.y) + (t.z + t.w);
      }

    // swap-trick butterfly over the 16-lane k-group: lane ks ends with batch (ks&3) sums.
    float v3[3];
#pragma unroll
    for (int q = 0; q < 3; q++) {
      const float s01 = (ks & 1) ? ha[0][q] : ha[1][q];
      const float r01 = __shfl_xor(s01, 1, 64);
      const float k01 = (ks & 1) ? ha[1][q] : ha[0][q];
      const float a01 = k01 + r01;          // batch (ks&1)
      const float s23 = (ks & 1) ? ha[2][q] : ha[3][q];
      const float r23 = __shfl_xor(s23, 1, 64);
      const float k23 = (ks & 1) ? ha[3][q] : ha[2][q];
      const float a23 = k23 + r23;          // batch (ks&1)+2
      const float s2 = (ks & 2) ? a01 : a23;
      const float r2 = __shfl_xor(s2, 2, 64);
      const float k2 = (ks & 2) ? a23 : a01;
      float t = k2 + r2;                    // batch (ks&3), partial over 4 k-slices
      t += __shfl_xor(t, 4, 64);
      t += __shfl_xor(t, 8, 64);
      v3[q] = t;
    }

    // gates: lanes ks<4 in every wave (batch=gb, unit=i)
    if (gate) {
      const float hr_ = bh0 + v3[0];
      const float hz_ = bh1 + v3[1];
      const float hn_ = bh2 + v3[2];
      const float r = 1.f / (1.f + expf(-(cxr + hr_)));
      const float z = 1.f / (1.f + expf(-(cxz + hz_)));
      const float n = tanhf(cxn + r * hn_);
      const float hp = hb[gb * 512 + hpIdx];
      const float hnew = (1.f - z) * n + z * hp;
      pmax = fmaxf(pmax, hnew);
      const float pv = __shfl_xor(hnew, 16, 64);  // partner unit i^1 (tid^16), also a gate lane
      if (!(iu & 1)) {
        const u32 abits = ((__float_as_uint(hnew) + 0x80u) >> 8) & 0xFFFFFFu;
        const u32 bbits = ((__float_as_uint(pv) + 0x80u) >> 8) & 0xFFFFFFu;
        const u64 pkt = ((u64)abits << 40) | ((u64)bbits << 16) | (u64)(u32)(s + 1);
        const int W = gb * 256 + (i >> 1);
        __hip_atomic_store(slot + (size_t)((s + 1) & 1) * 1024 + W, pkt,
                           __ATOMIC_RELAXED, __HIP_MEMORY_SCOPE_AGENT);
      }
    }

    // ---- wave-level agent-release + flag publish ----
    asm volatile("s_waitcnt vmcnt(0)" ::: "memory");
    if (ln == 0)
      __hip_atomic_store(fl + myflag, (u32)(s + 1), __ATOMIC_RELAXED, __HIP_MEMORY_SCOPE_AGENT);

    // prefetch next step's xi AFTER the release (a full step of latency to hide)
    float nxr = 0.f, nxz = 0.f, nxn = 0.f;
    if (gate && s + 1 < SS) {
      const size_t xo = ((size_t)(bbase + gb) * SS + (s + 1)) * G3 + i;
      nxr = toF(xi[xo]); nxz = toF(xi[xo + HDIM]); nxn = toF(xi[xo + 2 * HDIM]);
    }
    cxr = nxr; cxz = nxz; cxn = nxn;
  }

  if (gate) pooled[(size_t)(bbase + gb) * HDIM + i] = pmax;
}

// ---------------- K4: out = pooled @ W_proj^T + b_proj ----------------------------------------------
__global__ void k_out(const float* __restrict__ pooled, const float* __restrict__ W_proj,
                      const float* __restrict__ b_proj, float* __restrict__ out) {
  const int t = threadIdx.x;  // 64 threads
  const int b = t >> 1, c = t & 1;
  const float* p = pooled + (size_t)b * HDIM;
  const float* wr = W_proj + (size_t)c * HDIM;
  float acc = 0.f;
#pragma unroll 4
  for (int k = 0; k < HDIM; k += 4) {
    float4 pv = *(const float4*)(p + k);
    float4 wv = *(const float4*)(wr + k);
    acc += pv.x * wv.x + pv.y * wv.y + pv.z * wv.z + pv.w * wv.w;
  }
  out[b * CC + c] = acc + b_proj[c];
}

extern "C" void kernel_launch(void* const* d_in, const int* in_sizes, int n_in,
                              void* d_out, int out_size, void* d_ws, size_t ws_size,
                              hipStream_t stream) {
  const int* x = (const int*)d_in[0];
  const float* emb = (const float*)d_in[1];
  const float* unk = (const float*)d_in[2];
  const float* induction = (const float*)d_in[3];
  const float* W_ih = (const float*)d_in[4];
  const float* W_hh = (const float*)d_in[5];
  const float* b_ih = (const float*)d_in[6];
  const float* b_hh = (const float*)d_in[7];
  const float* W_proj = (const float*)d_in[8];
  const float* b_proj = (const float*)d_in[9];
  float* out = (float*)d_out;

  const size_t xi_f32 = (size_t)BB * SS * G3 * 4;
  const size_t xi_b16 = (size_t)BB * SS * G3 * 2;
  const size_t thw_sz = (size_t)8 * 2 * 1024 * 8 + 8192;  // 128KB data + 8KB flags
  const size_t tail = thw_sz + (size_t)BB * HDIM * 4 + EDIM * 4 + 4096;
  const bool usef32 = ws_size >= xi_f32 + tail;

  char* p = (char*)d_ws;
  void* xi = p;
  p += ((usef32 ? xi_f32 : xi_b16) + 255) & ~(size_t)255;
  u64* thw = (u64*)p;         p += thw_sz;
  float* pooled = (float*)p;  p += (size_t)BB * HDIM * 4;
  float* induced = (float*)p;

  k_init<<<18, 256, 0, stream>>>(induction, unk, induced, thw);
  if (usef32) {
    k_xi<float><<<dim3(12, 128), 256, 0, stream>>>(x, emb, induced, W_ih, b_ih, (float*)xi);
    k_gru<float><<<256, 256, 0, stream>>>((const float*)xi, W_hh, b_hh, thw, pooled);
  } else {
    k_xi<__hip_bfloat16><<<dim3(12, 128), 256, 0, stream>>>(x, emb, induced, W_ih, b_ih,
                                                            (__hip_bfloat16*)xi);
    k_gru<__hip_bfloat16><<<256, 256, 0, stream>>>((const __hip_bfloat16*)xi, W_hh, b_hh, thw, pooled);
  }
  k_out<<<1, 64, 0, stream>>>(pooled, W_proj, b_proj, out);
}

// Round 4
// 1783.076 us; speedup vs baseline: 2.8055x; 2.8055x over previous
//
#include <hip/hip_runtime.h>
#include <hip/hip_bf16.h>

#define EDIM 256
#define HDIM 512
#define BB 32
#define SS 512
#define CC 2
#define G3 1536   // 3*HDIM

typedef unsigned int u32;
typedef unsigned long long u64;
typedef __attribute__((ext_vector_type(8))) short short8;
typedef __attribute__((ext_vector_type(4))) float f32x4;

__device__ __forceinline__ float toF(float v) { return v; }
__device__ __forceinline__ float toF(__hip_bfloat16 v) { return __bfloat162float(v); }
__device__ __forceinline__ void storeX(float* p, float v) { *p = v; }
__device__ __forceinline__ void storeX(__hip_bfloat16* p, float v) { *p = __float2bfloat16(v); }

// fp32 -> bf16 bits, round-to-nearest-even (no dependence on __hip_bfloat16 internals)
__device__ __forceinline__ unsigned short f2bf(float f) {
  u32 b = __float_as_uint(f);
  return (unsigned short)((b + 0x7FFFu + ((b >> 16) & 1u)) >> 16);
}

// ---------------- K1: zero tagged h words (wgs 0..15) + induced vec (wg 16) ------------------------
__global__ void k_init(const float* __restrict__ induction, const float* __restrict__ unk_vec,
                       float* __restrict__ induced, u64* __restrict__ thw) {
  const int t = threadIdx.x;
  const int wg = blockIdx.x;
  if (wg < 16) {
    u64* p = thw + (size_t)wg * 1024;  // 16*1024 = 8 groups * 2 * 1024 data words
    for (int i = t; i < 1024; i += 256) p[i] = 0ull;
  } else {
    float acc = 0.f;
    const float* row = induction + t * EDIM;
#pragma unroll 4
    for (int j = 0; j < EDIM; j += 4) {
      float4 a = *(const float4*)(row + j);
      float4 u = *(const float4*)(unk_vec + j);
      acc += a.x * u.x + a.y * u.y + a.z * u.z + a.w * u.w;
    }
    induced[t] = acc;
  }
}

// ---------------- K2: xi = gather(e) @ W_ih^T + b_ih via bf16 MFMA ----------------------------------
// 128x128 tile, K-chunks of 32. A/B staged fp32->bf16 in LDS. mfma_f32_16x16x32_bf16.
template <typename XT>
__global__ __launch_bounds__(256) void k_xi(const int* __restrict__ x, const float* __restrict__ emb,
                                            const float* __restrict__ induced,
                                            const float* __restrict__ W_ih, const float* __restrict__ b_ih,
                                            XT* __restrict__ xi) {
  __shared__ __align__(16) unsigned short As[128][40];  // 32 k + 8 pad (80B rows, 16B-aligned)
  __shared__ __align__(16) unsigned short Bs[128][40];
  __shared__ int toks[128];
  __shared__ float bcol[128];
  const int c0 = blockIdx.x * 128;
  const int r0 = blockIdx.y * 128;
  const int tid = threadIdx.x;
  if (tid < 128) { toks[tid] = x[r0 + tid]; bcol[tid] = b_ih[c0 + tid]; }
  __syncthreads();

  const int wv = tid >> 6, ln = tid & 63;
  const int lr = tid & 127, kh = tid >> 7;   // staging: row, k-half (16 k's each)
  const int fm = ln & 15, fq = ln >> 4;      // fragment lane decomposition

  f32x4 acc[2][8];
#pragma unroll
  for (int i = 0; i < 2; i++)
#pragma unroll
    for (int j = 0; j < 8; j++) acc[i][j] = (f32x4){0.f, 0.f, 0.f, 0.f};

  const int tok = toks[lr];
  const float* abase = (tok < 0 ? induced : emb + (size_t)tok * EDIM) + kh * 16;
  const float* bbase = W_ih + (size_t)(c0 + lr) * EDIM + kh * 16;

  for (int kk = 0; kk < EDIM; kk += 32) {
    unsigned short av[16], bv[16];
#pragma unroll
    for (int q = 0; q < 4; q++) {
      float4 ta = *(const float4*)(abase + kk + q * 4);
      float4 tb = *(const float4*)(bbase + kk + q * 4);
      av[q * 4 + 0] = f2bf(ta.x); av[q * 4 + 1] = f2bf(ta.y);
      av[q * 4 + 2] = f2bf(ta.z); av[q * 4 + 3] = f2bf(ta.w);
      bv[q * 4 + 0] = f2bf(tb.x); bv[q * 4 + 1] = f2bf(tb.y);
      bv[q * 4 + 2] = f2bf(tb.z); bv[q * 4 + 3] = f2bf(tb.w);
    }
    *(uint4*)&As[lr][kh * 16 + 0] = *(uint4*)&av[0];
    *(uint4*)&As[lr][kh * 16 + 8] = *(uint4*)&av[8];
    *(uint4*)&Bs[lr][kh * 16 + 0] = *(uint4*)&bv[0];
    *(uint4*)&Bs[lr][kh * 16 + 8] = *(uint4*)&bv[8];
    __syncthreads();

    short8 af0 = *(const short8*)&As[wv * 32 + fm][fq * 8];
    short8 af1 = *(const short8*)&As[wv * 32 + 16 + fm][fq * 8];
#pragma unroll
    for (int ni = 0; ni < 8; ni++) {
      short8 bf = *(const short8*)&Bs[ni * 16 + fm][fq * 8];
      acc[0][ni] = __builtin_amdgcn_mfma_f32_16x16x32_bf16(af0, bf, acc[0][ni], 0, 0, 0);
      acc[1][ni] = __builtin_amdgcn_mfma_f32_16x16x32_bf16(af1, bf, acc[1][ni], 0, 0, 0);
    }
    __syncthreads();
  }

#pragma unroll
  for (int mi = 0; mi < 2; mi++)
#pragma unroll
    for (int ni = 0; ni < 8; ni++) {
      const int col = c0 + ni * 16 + fm;
      const float bb = bcol[ni * 16 + fm];
#pragma unroll
      for (int r = 0; r < 4; r++) {
        const int row = r0 + wv * 32 + mi * 16 + fq * 4 + r;
        storeX(xi + (size_t)row * G3 + col, acc[mi][ni][r] + bb);
      }
    }
}

// ---------------- K3: persistent GRU, pair-staggered phases over R1's tagged exchange --------------
// 8 groups x 32 wgs. Data word W = c*256+p: 24-bit mantissa fp32 pair + 16-bit step tag, relaxed
// agent-scope u64, double-buffered by step parity (R1 protocol, proven).
//
// Each step runs TWO phases. Phase P handles batches {2P, 2P+1}: poll+stage that pair's words ->
// barrier -> dots/reduce/gates/publish for the pair. The words phase A of step s+1 needs were
// published at the END of phase A of step s, i.e. a full phase-B of compute before they are needed
// -> publish-visibility + poll-detect latency hides behind the other pair's compute.
// Per-pair double-buffer overwrite-safety argument is identical to R1's (2-step lag).
template <typename XT>
__global__ __launch_bounds__(256, 1) void k_gru(const XT* __restrict__ xi, const float* __restrict__ W_hh,
                                                const float* __restrict__ b_hh, u64* __restrict__ thw,
                                                float* __restrict__ pooled) {
  const int wg = blockIdx.x;
  const int g = wg & 7;          // group (mod-8 keeps a group's wgs on one XCD)
  const int m = wg >> 3;         // 0..31
  const int bbase = g * 4;
  const int i0 = m * 16;
  const int tid = threadIdx.x;
  const int iu = tid >> 4;       // 0..15: unit within wg slice
  const int ks = tid & 15;       // 0..15: k-slice, k in [ks*32, ks*32+32)
  const int i = i0 + iu;         // global unit
  const int swz = ks & 7;        // LDS chunk swizzle for this lane's window

  // per-thread W_hh slice: 3 gates x 32 k as 8 float4 (96 VGPRs; occupancy is 1 wave/SIMD anyway)
  f32x4 w[3][8];
#pragma unroll
  for (int q = 0; q < 3; q++) {
    const float* wr = W_hh + (size_t)(q * HDIM + i) * HDIM + ks * 32;
#pragma unroll
    for (int j = 0; j < 8; j++) w[q][j] = *(const f32x4*)(wr + j * 4);
  }
  const float bh0 = b_hh[i], bh1 = b_hh[HDIM + i], bh2 = b_hh[2 * HDIM + i];

  const bool gate = (ks < 2);    // 2 gate lanes per 16-group; batch = 2*P + ks in phase P
  // h_prev read index for unit i in a swizzled row: chunk Q=i>>2, phys=Q^((Q>>3)&7), elem=i&3
  const int hpIdx = ((((i >> 2) ^ ((i >> 5) & 7)) << 2) | (i & 3));
  // staging write offset for pair p=tid: chunk Q=tid>>1, phys=Q^((Q>>3)&7), elem=(tid&1)*2
  const int foff = ((((tid >> 1) ^ ((tid >> 4) & 7)) << 2) | ((tid & 1) << 1));

  u64* slot = thw + (size_t)g * 2 * 1024;
  __shared__ __align__(16) float hs[2][4][512];

  float pmax[2] = {-3.0e38f, -3.0e38f};

  float cx[2][3] = {{0.f, 0.f, 0.f}, {0.f, 0.f, 0.f}};
  if (gate) {
#pragma unroll
    for (int P = 0; P < 2; P++) {
      const size_t xo = (size_t)(bbase + 2 * P + ks) * SS * G3 + i;
      cx[P][0] = toF(xi[xo]); cx[P][1] = toF(xi[xo + HDIM]); cx[P][2] = toF(xi[xo + 2 * HDIM]);
    }
  }

  for (int s = 0; s < SS; s++) {
    // prefetch next step's xi a full step ahead (hidden under both phases)
    float nx[2][3] = {{0.f, 0.f, 0.f}, {0.f, 0.f, 0.f}};
    if (gate && s + 1 < SS) {
#pragma unroll
      for (int P = 0; P < 2; P++) {
        const size_t xo = ((size_t)(bbase + 2 * P + ks) * SS + (s + 1)) * G3 + i;
        nx[P][0] = toF(xi[xo]); nx[P][1] = toF(xi[xo + HDIM]); nx[P][2] = toF(xi[xo + 2 * HDIM]);
      }
    }

    float* hb = &hs[s & 1][0][0];

#pragma unroll
    for (int P = 0; P < 2; P++) {
      // ---- poll + stage this pair's words (R1 tagged protocol, 2 words/thread) ----
      if (s == 0) {
        if (P == 0) {
#pragma unroll
          for (int t = 0; t < 8; t++) hb[t * 256 + tid] = 0.f;
        }
      } else {
        const u32 need = (u32)s;
        const u64* src = slot + (size_t)(s & 1) * 1024 + 2 * P * 256 + tid;
        u64 v0 = __hip_atomic_load(src, __ATOMIC_RELAXED, __HIP_MEMORY_SCOPE_AGENT);
        u64 v1 = __hip_atomic_load(src + 256, __ATOMIC_RELAXED, __HIP_MEMORY_SCOPE_AGENT);
        int guard = 0;
        while ((((u32)(v0 & 0xFFFFu) != need) || ((u32)(v1 & 0xFFFFu) != need)) && guard < (1 << 18)) {
          __builtin_amdgcn_s_sleep(1);
          if ((u32)(v0 & 0xFFFFu) != need)
            v0 = __hip_atomic_load(src, __ATOMIC_RELAXED, __HIP_MEMORY_SCOPE_AGENT);
          if ((u32)(v1 & 0xFFFFu) != need)
            v1 = __hip_atomic_load(src + 256, __ATOMIC_RELAXED, __HIP_MEMORY_SCOPE_AGENT);
          guard++;
        }
        {
          const float a0 = __uint_as_float((u32)(v0 >> 40) << 8);
          const float b0 = __uint_as_float((u32)((v0 >> 16) & 0xFFFFFFu) << 8);
          *(float2*)&hb[(2 * P) * 512 + foff] = make_float2(a0, b0);
          const float a1 = __uint_as_float((u32)(v1 >> 40) << 8);
          const float b1 = __uint_as_float((u32)((v1 >> 16) & 0xFFFFFFu) << 8);
          *(float2*)&hb[(2 * P + 1) * 512 + foff] = make_float2(a1, b1);
        }
      }
      __syncthreads();

      // ---- dots for this pair: 2 batches x 3 gates over the 32-k window ----
      f32x4 acc[2][3];
#pragma unroll
      for (int b = 0; b < 2; b++)
#pragma unroll
        for (int q = 0; q < 3; q++) acc[b][q] = (f32x4){0.f, 0.f, 0.f, 0.f};

#pragma unroll
      for (int b = 0; b < 2; b++) {
        const float* hr = hb + (2 * P + b) * 512 + ks * 32;
#pragma unroll
        for (int j = 0; j < 8; j++) {
          const f32x4 hv = *(const f32x4*)(hr + ((j ^ swz) << 2));  // logical chunk j
          acc[b][0] = __builtin_elementwise_fma(w[0][j], hv, acc[b][0]);
          acc[b][1] = __builtin_elementwise_fma(w[1][j], hv, acc[b][1]);
          acc[b][2] = __builtin_elementwise_fma(w[2][j], hv, acc[b][2]);
        }
      }

      float ha[2][3];
#pragma unroll
      for (int b = 0; b < 2; b++)
#pragma unroll
        for (int q = 0; q < 3; q++) {
          const f32x4 t = acc[b][q];
          ha[b][q] = (t.x + t.y) + (t.z + t.w);
        }

      // butterfly over the 16-lane k-group: lane ks ends with batch 2P+(ks&1) sums.
      float v3[3];
#pragma unroll
      for (int q = 0; q < 3; q++) {
        const float s01 = (ks & 1) ? ha[0][q] : ha[1][q];
        const float r01 = __shfl_xor(s01, 1, 64);
        const float k01 = (ks & 1) ? ha[1][q] : ha[0][q];
        float t = k01 + r01;                 // batch 2P+(ks&1), 2 k-windows
        t += __shfl_xor(t, 2, 64);
        t += __shfl_xor(t, 4, 64);
        t += __shfl_xor(t, 8, 64);
        v3[q] = t;
      }

      // gates: lanes ks<2 in every wave (batch = 2P+ks, unit = i)
      if (gate) {
        const float hr_ = bh0 + v3[0];
        const float hz_ = bh1 + v3[1];
        const float hn_ = bh2 + v3[2];
        const float r = 1.f / (1.f + expf(-(cx[P][0] + hr_)));
        const float z = 1.f / (1.f + expf(-(cx[P][1] + hz_)));
        const float n = tanhf(cx[P][2] + r * hn_);
        const float hp = hb[(2 * P + ks) * 512 + hpIdx];
        const float hnew = (1.f - z) * n + z * hp;
        pmax[P] = fmaxf(pmax[P], hnew);
        const float pv = __shfl_xor(hnew, 16, 64);  // partner unit i^1 (tid^16), also a gate lane
        if (!(iu & 1)) {
          const u32 abits = ((__float_as_uint(hnew) + 0x80u) >> 8) & 0xFFFFFFu;
          const u32 bbits = ((__float_as_uint(pv) + 0x80u) >> 8) & 0xFFFFFFu;
          const u64 pkt = ((u64)abits << 40) | ((u64)bbits << 16) | (u64)(u32)(s + 1);
          const int W = (2 * P + ks) * 256 + (i >> 1);
          __hip_atomic_store(slot + (size_t)((s + 1) & 1) * 1024 + W, pkt,
                             __ATOMIC_RELAXED, __HIP_MEMORY_SCOPE_AGENT);
        }
      }
    }

#pragma unroll
    for (int P = 0; P < 2; P++) {
      cx[P][0] = nx[P][0]; cx[P][1] = nx[P][1]; cx[P][2] = nx[P][2];
    }
  }

  if (gate) {
    pooled[(size_t)(bbase + ks) * HDIM + i] = pmax[0];
    pooled[(size_t)(bbase + 2 + ks) * HDIM + i] = pmax[1];
  }
}

// ---------------- K4: out = pooled @ W_proj^T + b_proj ----------------------------------------------
__global__ void k_out(const float* __restrict__ pooled, const float* __restrict__ W_proj,
                      const float* __restrict__ b_proj, float* __restrict__ out) {
  const int t = threadIdx.x;  // 64 threads
  const int b = t >> 1, c = t & 1;
  const float* p = pooled + (size_t)b * HDIM;
  const float* wr = W_proj + (size_t)c * HDIM;
  float acc = 0.f;
#pragma unroll 4
  for (int k = 0; k < HDIM; k += 4) {
    float4 pv = *(const float4*)(p + k);
    float4 wv = *(const float4*)(wr + k);
    acc += pv.x * wv.x + pv.y * wv.y + pv.z * wv.z + pv.w * wv.w;
  }
  out[b * CC + c] = acc + b_proj[c];
}

extern "C" void kernel_launch(void* const* d_in, const int* in_sizes, int n_in,
                              void* d_out, int out_size, void* d_ws, size_t ws_size,
                              hipStream_t stream) {
  const int* x = (const int*)d_in[0];
  const float* emb = (const float*)d_in[1];
  const float* unk = (const float*)d_in[2];
  const float* induction = (const float*)d_in[3];
  const float* W_ih = (const float*)d_in[4];
  const float* W_hh = (const float*)d_in[5];
  const float* b_ih = (const float*)d_in[6];
  const float* b_hh = (const float*)d_in[7];
  const float* W_proj = (const float*)d_in[8];
  const float* b_proj = (const float*)d_in[9];
  float* out = (float*)d_out;

  const size_t xi_f32 = (size_t)BB * SS * G3 * 4;
  const size_t xi_b16 = (size_t)BB * SS * G3 * 2;
  const size_t thw_sz = (size_t)8 * 2 * 1024 * 8;  // 128 KB
  const size_t tail = thw_sz + (size_t)BB * HDIM * 4 + EDIM * 4 + 4096;
  const bool usef32 = ws_size >= xi_f32 + tail;

  char* p = (char*)d_ws;
  void* xi = p;
  p += ((usef32 ? xi_f32 : xi_b16) + 255) & ~(size_t)255;
  u64* thw = (u64*)p;         p += thw_sz;
  float* pooled = (float*)p;  p += (size_t)BB * HDIM * 4;
  float* induced = (float*)p;

  k_init<<<17, 256, 0, stream>>>(induction, unk, induced, thw);
  if (usef32) {
    k_xi<float><<<dim3(12, 128), 256, 0, stream>>>(x, emb, induced, W_ih, b_ih, (float*)xi);
    k_gru<float><<<256, 256, 0, stream>>>((const float*)xi, W_hh, b_hh, thw, pooled);
  } else {
    k_xi<__hip_bfloat16><<<dim3(12, 128), 256, 0, stream>>>(x, emb, induced, W_ih, b_ih,
                                                            (__hip_bfloat16*)xi);
    k_gru<__hip_bfloat16><<<256, 256, 0, stream>>>((const __hip_bfloat16*)xi, W_hh, b_hh, thw, pooled);
  }
  k_out<<<1, 64, 0, stream>>>(pooled, W_proj, b_proj, out);
}

// Round 5
// 1482.786 us; speedup vs baseline: 3.3736x; 1.2025x over previous
//
#include <hip/hip_runtime.h>
#include <hip/hip_bf16.h>

#define EDIM 256
#define HDIM 512
#define BB 32
#define SS 512
#define CC 2
#define G3 1536   // 3*HDIM

typedef unsigned int u32;
typedef unsigned long long u64;
typedef __attribute__((ext_vector_type(8))) short short8;
typedef __attribute__((ext_vector_type(4))) float f32x4;

__device__ __forceinline__ float toF(float v) { return v; }
__device__ __forceinline__ float toF(__hip_bfloat16 v) { return __bfloat162float(v); }
__device__ __forceinline__ void storeX(float* p, float v) { *p = v; }
__device__ __forceinline__ void storeX(__hip_bfloat16* p, float v) { *p = __float2bfloat16(v); }

// fp32 -> bf16 bits, round-to-nearest-even (no dependence on __hip_bfloat16 internals)
__device__ __forceinline__ unsigned short f2bf(float f) {
  u32 b = __float_as_uint(f);
  return (unsigned short)((b + 0x7FFFu + ((b >> 16) & 1u)) >> 16);
}

// ---------------- K1: zero tagged h words (wgs 0..15) + induced vec (wg 16) ------------------------
__global__ void k_init(const float* __restrict__ induction, const float* __restrict__ unk_vec,
                       float* __restrict__ induced, u64* __restrict__ thw) {
  const int t = threadIdx.x;
  const int wg = blockIdx.x;
  if (wg < 16) {
    u64* p = thw + (size_t)wg * 1024;  // 16*1024 = 8 groups * 2 * 1024 data words
    for (int i = t; i < 1024; i += 256) p[i] = 0ull;
  } else {
    float acc = 0.f;
    const float* row = induction + t * EDIM;
#pragma unroll 4
    for (int j = 0; j < EDIM; j += 4) {
      float4 a = *(const float4*)(row + j);
      float4 u = *(const float4*)(unk_vec + j);
      acc += a.x * u.x + a.y * u.y + a.z * u.z + a.w * u.w;
    }
    induced[t] = acc;
  }
}

// ---------------- K2: xi = gather(e) @ W_ih^T + b_ih via bf16 MFMA ----------------------------------
// 128x128 tile, K-chunks of 32. A/B staged fp32->bf16 in LDS. mfma_f32_16x16x32_bf16.
template <typename XT>
__global__ __launch_bounds__(256) void k_xi(const int* __restrict__ x, const float* __restrict__ emb,
                                            const float* __restrict__ induced,
                                            const float* __restrict__ W_ih, const float* __restrict__ b_ih,
                                            XT* __restrict__ xi) {
  __shared__ __align__(16) unsigned short As[128][40];  // 32 k + 8 pad (80B rows, 16B-aligned)
  __shared__ __align__(16) unsigned short Bs[128][40];
  __shared__ int toks[128];
  __shared__ float bcol[128];
  const int c0 = blockIdx.x * 128;
  const int r0 = blockIdx.y * 128;
  const int tid = threadIdx.x;
  if (tid < 128) { toks[tid] = x[r0 + tid]; bcol[tid] = b_ih[c0 + tid]; }
  __syncthreads();

  const int wv = tid >> 6, ln = tid & 63;
  const int lr = tid & 127, kh = tid >> 7;   // staging: row, k-half (16 k's each)
  const int fm = ln & 15, fq = ln >> 4;      // fragment lane decomposition

  f32x4 acc[2][8];
#pragma unroll
  for (int i = 0; i < 2; i++)
#pragma unroll
    for (int j = 0; j < 8; j++) acc[i][j] = (f32x4){0.f, 0.f, 0.f, 0.f};

  const int tok = toks[lr];
  const float* abase = (tok < 0 ? induced : emb + (size_t)tok * EDIM) + kh * 16;
  const float* bbase = W_ih + (size_t)(c0 + lr) * EDIM + kh * 16;

  for (int kk = 0; kk < EDIM; kk += 32) {
    unsigned short av[16], bv[16];
#pragma unroll
    for (int q = 0; q < 4; q++) {
      float4 ta = *(const float4*)(abase + kk + q * 4);
      float4 tb = *(const float4*)(bbase + kk + q * 4);
      av[q * 4 + 0] = f2bf(ta.x); av[q * 4 + 1] = f2bf(ta.y);
      av[q * 4 + 2] = f2bf(ta.z); av[q * 4 + 3] = f2bf(ta.w);
      bv[q * 4 + 0] = f2bf(tb.x); bv[q * 4 + 1] = f2bf(tb.y);
      bv[q * 4 + 2] = f2bf(tb.z); bv[q * 4 + 3] = f2bf(tb.w);
    }
    *(uint4*)&As[lr][kh * 16 + 0] = *(uint4*)&av[0];
    *(uint4*)&As[lr][kh * 16 + 8] = *(uint4*)&av[8];
    *(uint4*)&Bs[lr][kh * 16 + 0] = *(uint4*)&bv[0];
    *(uint4*)&Bs[lr][kh * 16 + 8] = *(uint4*)&bv[8];
    __syncthreads();

    short8 af0 = *(const short8*)&As[wv * 32 + fm][fq * 8];
    short8 af1 = *(const short8*)&As[wv * 32 + 16 + fm][fq * 8];
#pragma unroll
    for (int ni = 0; ni < 8; ni++) {
      short8 bf = *(const short8*)&Bs[ni * 16 + fm][fq * 8];
      acc[0][ni] = __builtin_amdgcn_mfma_f32_16x16x32_bf16(af0, bf, acc[0][ni], 0, 0, 0);
      acc[1][ni] = __builtin_amdgcn_mfma_f32_16x16x32_bf16(af1, bf, acc[1][ni], 0, 0, 0);
    }
    __syncthreads();
  }

#pragma unroll
  for (int mi = 0; mi < 2; mi++)
#pragma unroll
    for (int ni = 0; ni < 8; ni++) {
      const int col = c0 + ni * 16 + fm;
      const float bb = bcol[ni * 16 + fm];
#pragma unroll
      for (int r = 0; r < 4; r++) {
        const int row = r0 + wv * 32 + mi * 16 + fq * 4 + r;
        storeX(xi + (size_t)row * G3 + col, acc[mi][ni][r] + bb);
      }
    }
}

// ---------------- K3: persistent GRU, R1 structure + cross-iteration pipelined polls ---------------
// 8 groups x 32 wgs. Word W = c*256+p: 24-bit mantissa fp32 pair + 16-bit step tag, relaxed
// agent-scope u64, double-buffered by step parity (R1 protocol, measured 1505us).
//
// R5 change (vmcnt FIFO fix): poll loads for step s+1 are ISSUED late in step s (after butterfly,
// BEFORE the publish store). At step s+1's first tag check they are the OLDEST outstanding vmem ops,
// so the compiler's waitcnt is vmcnt(4) (store + 3 xi prefetches are newer) -- the first check no
// longer drains the freshly-issued ~900cy HBM xi prefetch (which vmcnt(0) did in R0/R1/R4, since
// s_waitcnt vmcnt(N) retires OLDEST-first). Spin re-loads still imply vmcnt(0), but that drain
// happens while waiting anyway (free). Everything else is identical to R1.
template <typename XT>
__global__ __launch_bounds__(256, 1) void k_gru(const XT* __restrict__ xi, const float* __restrict__ W_hh,
                                                const float* __restrict__ b_hh, u64* __restrict__ thw,
                                                float* __restrict__ pooled) {
  const int wg = blockIdx.x;
  const int g = wg & 7;          // group (mod-8 keeps a group's wgs on one XCD)
  const int m = wg >> 3;         // 0..31
  const int bbase = g * 4;
  const int i0 = m * 16;
  const int tid = threadIdx.x;
  const int iu = tid >> 4;       // 0..15: unit within wg slice
  const int ks = tid & 15;       // 0..15: k-slice, k in [ks*32, ks*32+32)
  const int i = i0 + iu;         // global unit
  const int swz = ks & 7;        // LDS chunk swizzle for this lane's window

  // per-thread W_hh slice: 3 gates x 32 k as 8 float4 (96 VGPRs; occupancy is 1 wave/SIMD anyway)
  f32x4 w[3][8];
#pragma unroll
  for (int q = 0; q < 3; q++) {
    const float* wr = W_hh + (size_t)(q * HDIM + i) * HDIM + ks * 32;
#pragma unroll
    for (int j = 0; j < 8; j++) w[q][j] = *(const f32x4*)(wr + j * 4);
  }
  const float bh0 = b_hh[i], bh1 = b_hh[HDIM + i], bh2 = b_hh[2 * HDIM + i];

  const bool gate = (ks < 4);
  const int gb = ks & 3;         // batch-in-group for gate lanes
  // h_prev read index for unit i in a swizzled row: chunk Q=i>>2, phys=Q^((Q>>3)&7), elem=i&3
  const int hpIdx = ((((i >> 2) ^ ((i >> 5) & 7)) << 2) | (i & 3));
  // staging write offset for pair p=tid: chunk Q=tid>>1, phys=Q^((Q>>3)&7), elem=(tid&1)*2
  const int foff = ((((tid >> 1) ^ ((tid >> 4) & 7)) << 2) | ((tid & 1) << 1));

  u64* slot = thw + (size_t)g * 2 * 1024;
  __shared__ __align__(16) float hs[2][4][512];

  float pmax = -3.0e38f;

  float cxr = 0.f, cxz = 0.f, cxn = 0.f;
  if (gate) {
    const size_t xo = (size_t)(bbase + gb) * SS * G3 + i;
    cxr = toF(xi[xo]); cxz = toF(xi[xo + HDIM]); cxn = toF(xi[xo + 2 * HDIM]);
  }

  u64 v[4];  // pipelined poll words: issued late in step s, checked at step s+1

  for (int s = 0; s < SS; s++) {
    // xi prefetch for s+1: issued at top, consumed at next step's gates (~a full step of slack).
    float nxr = 0.f, nxz = 0.f, nxn = 0.f;
    if (gate && s + 1 < SS) {
      const size_t xo = ((size_t)(bbase + gb) * SS + (s + 1)) * G3 + (i0 + (tid >> 4));
      nxr = toF(xi[xo]); nxz = toF(xi[xo + HDIM]); nxn = toF(xi[xo + 2 * HDIM]);
    }

    float* hb = &hs[s & 1][0][0];
    if (s == 0) {
#pragma unroll
      for (int t = 0; t < 8; t++) hb[t * 256 + tid] = 0.f;
    } else {
      const u32 need = (u32)s;
      // first check on the PIPELINED loads (oldest outstanding -> no prefetch drain)
      u32 pend = 0;
#pragma unroll
      for (int j = 0; j < 4; j++)
        if ((u32)(v[j] & 0xFFFFu) != need) pend |= 1u << j;
      const u64* src = slot + (size_t)(s & 1) * 1024 + tid;  // W = j*256+tid -> chain j, pair tid
      int guard = 0;
      while (pend && guard < (1 << 18)) {
        __builtin_amdgcn_s_sleep(1);
#pragma unroll
        for (int j = 0; j < 4; j++)
          if (pend & (1u << j))
            v[j] = __hip_atomic_load(src + j * 256, __ATOMIC_RELAXED, __HIP_MEMORY_SCOPE_AGENT);
#pragma unroll
        for (int j = 0; j < 4; j++)
          if ((pend & (1u << j)) && (u32)(v[j] & 0xFFFFu) == need) pend &= ~(1u << j);
        guard++;
      }
#pragma unroll
      for (int j = 0; j < 4; j++) {
        const float a = __uint_as_float((u32)(v[j] >> 40) << 8);
        const float b = __uint_as_float((u32)((v[j] >> 16) & 0xFFFFFFu) << 8);
        *(float2*)&hb[j * 512 + foff] = make_float2(a, b);
      }
    }
    __syncthreads();  // the ONLY barrier per step

    // dots: 4 batches x 3 gates over this lane's 32-k window (float4 lanes, swizzled chunks)
    f32x4 acc[4][3];
#pragma unroll
    for (int b = 0; b < 4; b++)
#pragma unroll
      for (int q = 0; q < 3; q++) acc[b][q] = (f32x4){0.f, 0.f, 0.f, 0.f};

#pragma unroll
    for (int b = 0; b < 4; b++) {
      const float* hr = hb + b * 512 + ks * 32;
#pragma unroll
      for (int j = 0; j < 8; j++) {
        const f32x4 hv = *(const f32x4*)(hr + ((j ^ swz) << 2));  // logical chunk j
        acc[b][0] = __builtin_elementwise_fma(w[0][j], hv, acc[b][0]);
        acc[b][1] = __builtin_elementwise_fma(w[1][j], hv, acc[b][1]);
        acc[b][2] = __builtin_elementwise_fma(w[2][j], hv, acc[b][2]);
      }
    }

    // horizontal collapse to 12 scalars
    float ha[4][3];
#pragma unroll
    for (int b = 0; b < 4; b++)
#pragma unroll
      for (int q = 0; q < 3; q++) {
        const f32x4 t = acc[b][q];
        ha[b][q] = (t.x + t.y) + (t.z + t.w);
      }

    // swap-trick butterfly over the 16-lane k-group: lane ks ends with batch (ks&3) sums.
    float v3[3];
#pragma unroll
    for (int q = 0; q < 3; q++) {
      const float s01 = (ks & 1) ? ha[0][q] : ha[1][q];
      const float r01 = __shfl_xor(s01, 1, 64);
      const float k01 = (ks & 1) ? ha[1][q] : ha[0][q];
      const float a01 = k01 + r01;          // batch (ks&1)
      const float s23 = (ks & 1) ? ha[2][q] : ha[3][q];
      const float r23 = __shfl_xor(s23, 1, 64);
      const float k23 = (ks & 1) ? ha[3][q] : ha[2][q];
      const float a23 = k23 + r23;          // batch (ks&1)+2
      const float s2 = (ks & 2) ? a01 : a23;
      const float r2 = __shfl_xor(s2, 2, 64);
      const float k2 = (ks & 2) ? a23 : a01;
      float t = k2 + r2;                    // batch (ks&3), partial over 4 k-slices
      t += __shfl_xor(t, 4, 64);
      t += __shfl_xor(t, 8, 64);
      v3[q] = t;
    }

    // ---- pipelined poll ISSUE for s+1: before the publish store, so at the next step's check
    // these are the oldest outstanding vmem ops (waitcnt ~ vmcnt(4), no HBM drain).
    if (s + 1 < SS) {
      const u64* nsrc = slot + (size_t)((s + 1) & 1) * 1024 + tid;
#pragma unroll
      for (int j = 0; j < 4; j++)
        v[j] = __hip_atomic_load(nsrc + j * 256, __ATOMIC_RELAXED, __HIP_MEMORY_SCOPE_AGENT);
    }

    // gates: lanes ks<4 in every wave (batch=gb, unit=i)
    if (gate) {
      const float hr_ = bh0 + v3[0];
      const float hz_ = bh1 + v3[1];
      const float hn_ = bh2 + v3[2];
      const float r = 1.f / (1.f + expf(-(cxr + hr_)));
      const float z = 1.f / (1.f + expf(-(cxz + hz_)));
      const float n = tanhf(cxn + r * hn_);
      const float hp = hb[gb * 512 + hpIdx];
      const float hnew = (1.f - z) * n + z * hp;
      pmax = fmaxf(pmax, hnew);
      const float pv = __shfl_xor(hnew, 16, 64);  // partner unit i^1 (tid^16), also a gate lane
      if (!(iu & 1)) {
        const u32 abits = ((__float_as_uint(hnew) + 0x80u) >> 8) & 0xFFFFFFu;
        const u32 bbits = ((__float_as_uint(pv) + 0x80u) >> 8) & 0xFFFFFFu;
        const u64 pkt = ((u64)abits << 40) | ((u64)bbits << 16) | (u64)(u32)(s + 1);
        const int W = gb * 256 + (i >> 1);
        __hip_atomic_store(slot + (size_t)((s + 1) & 1) * 1024 + W, pkt,
                           __ATOMIC_RELAXED, __HIP_MEMORY_SCOPE_AGENT);
      }
    }
    cxr = nxr; cxz = nxz; cxn = nxn;
  }

  if (gate) pooled[(size_t)(bbase + gb) * HDIM + i] = pmax;
}

// ---------------- K4: out = pooled @ W_proj^T + b_proj ----------------------------------------------
__global__ void k_out(const float* __restrict__ pooled, const float* __restrict__ W_proj,
                      const float* __restrict__ b_proj, float* __restrict__ out) {
  const int t = threadIdx.x;  // 64 threads
  const int b = t >> 1, c = t & 1;
  const float* p = pooled + (size_t)b * HDIM;
  const float* wr = W_proj + (size_t)c * HDIM;
  float acc = 0.f;
#pragma unroll 4
  for (int k = 0; k < HDIM; k += 4) {
    float4 pv = *(const float4*)(p + k);
    float4 wv = *(const float4*)(wr + k);
    acc += pv.x * wv.x + pv.y * wv.y + pv.z * wv.z + pv.w * wv.w;
  }
  out[b * CC + c] = acc + b_proj[c];
}

extern "C" void kernel_launch(void* const* d_in, const int* in_sizes, int n_in,
                              void* d_out, int out_size, void* d_ws, size_t ws_size,
                              hipStream_t stream) {
  const int* x = (const int*)d_in[0];
  const float* emb = (const float*)d_in[1];
  const float* unk = (const float*)d_in[2];
  const float* induction = (const float*)d_in[3];
  const float* W_ih = (const float*)d_in[4];
  const float* W_hh = (const float*)d_in[5];
  const float* b_ih = (const float*)d_in[6];
  const float* b_hh = (const float*)d_in[7];
  const float* W_proj = (const float*)d_in[8];
  const float* b_proj = (const float*)d_in[9];
  float* out = (float*)d_out;

  const size_t xi_f32 = (size_t)BB * SS * G3 * 4;
  const size_t xi_b16 = (size_t)BB * SS * G3 * 2;
  const size_t thw_sz = (size_t)8 * 2 * 1024 * 8;  // 128 KB
  const size_t tail = thw_sz + (size_t)BB * HDIM * 4 + EDIM * 4 + 4096;
  const bool usef32 = ws_size >= xi_f32 + tail;

  char* p = (char*)d_ws;
  void* xi = p;
  p += ((usef32 ? xi_f32 : xi_b16) + 255) & ~(size_t)255;
  u64* thw = (u64*)p;         p += thw_sz;
  float* pooled = (float*)p;  p += (size_t)BB * HDIM * 4;
  float* induced = (float*)p;

  k_init<<<17, 256, 0, stream>>>(induction, unk, induced, thw);
  if (usef32) {
    k_xi<float><<<dim3(12, 128), 256, 0, stream>>>(x, emb, induced, W_ih, b_ih, (float*)xi);
    k_gru<float><<<256, 256, 0, stream>>>((const float*)xi, W_hh, b_hh, thw, pooled);
  } else {
    k_xi<__hip_bfloat16><<<dim3(12, 128), 256, 0, stream>>>(x, emb, induced, W_ih, b_ih,
                                                            (__hip_bfloat16*)xi);
    k_gru<__hip_bfloat16><<<256, 256, 0, stream>>>((const __hip_bfloat16*)xi, W_hh, b_hh, thw, pooled);
  }
  k_out<<<1, 64, 0, stream>>>(pooled, W_proj, b_proj, out);
}